// Round 7
// baseline (422.346 us; speedup 1.0000x reference)
//
#include <hip/hip_runtime.h>
#include <math.h>

// downprompt: fused elementwise + 7-way cosine-sim + softmax.
// v8: cache-partition the two input streams. Evidence: v0/v3/v7 (three
// different schedules, 2x range of in-flight bytes) all converge at
// ~2.9 TB/s delivered -> memory SERVICE rate is the limit, not MLP.
// Working set 410MB thrashes the 256MB L3 (~50% hit), so L3 banks carry
// hits + fills = 410MB/dispatch. Fix: seq loads are NON-TEMPORAL (no
// L3/L2 allocation) -> seq streams from HBM and stops evicting seq1;
// seq1 (200MB) becomes fully L3-resident, zero fill traffic.
// Structure: simple v3-style loop (LDS-DMA ring bought nothing), 4
// lanes/row x 16 rows/wave, coef+ave in LDS broadcast, 2-round quad
// reduction, x4-redundant softmax epilogue. 12500 waves, 1 group each.

typedef float f32x4 __attribute__((ext_vector_type(4)));

__device__ __forceinline__ float elu1(float x) {
    return x > 0.0f ? x : __expf(x) - 1.0f;
}

__device__ __forceinline__ float wave_sum(float v) {
#pragma unroll
    for (int off = 32; off > 0; off >>= 1)
        v += __shfl_xor(v, off, 64);
    return v;
}

__global__ __launch_bounds__(256) void downprompt_kernel(
    const float* __restrict__ seq,
    const float* __restrict__ seq1,
    const float* __restrict__ prompt,
    const float* __restrict__ w_np,
    const float* __restrict__ w_ds,
    const float* __restrict__ w_df,
    const float* __restrict__ ave,
    float* __restrict__ out,
    int N)
{
    __shared__ float s_coef[256];
    __shared__ float s_ave[7][256];

    const int tid  = threadIdx.x;
    const int lane = tid & 63;

    // ---- block setup: stage coef[d] and ave into LDS ----
    {
        const float a  = w_df[0];
        const float b  = w_df[1];
        const float w0 = w_np[0], w1 = w_np[1], w2 = w_np[2];
        const float pr = w0 * prompt[tid] + w1 * prompt[256 + tid]
                       + w2 * prompt[512 + tid];
        s_coef[tid] = a * (1.0f + elu1(pr)) + b * w_ds[tid];
#pragma unroll
        for (int c = 0; c < 7; ++c)
            s_ave[c][tid] = ave[c * 256 + tid];
    }
    __syncthreads();

    // ---- per-wave: prototype norms (once per wave) ----
    float na[7];
#pragma unroll
    for (int c = 0; c < 7; ++c) {
        const float4 v = *(const float4*)&s_ave[c][lane << 2];
        na[c] = sqrtf(wave_sum(v.x * v.x + v.y * v.y + v.z * v.z + v.w * v.w));
    }

    // ---- 4 lanes per row, 16 rows per wave ----
    const int q   = lane & 3;    // column phase (0..3)
    const int q4  = q << 2;
    const int sub = lane >> 2;   // row within group (0..15)
    const int wavesPerBlock = blockDim.x >> 6;
    const int gwave = blockIdx.x * wavesPerBlock + (tid >> 6);
    const int nwave = gridDim.x * wavesPerBlock;
    const int ngroups = (N + 15) >> 4;

    for (int g = gwave; g < ngroups; g += nwave) {
        const int row = (g << 4) + sub;
        if (row >= N) continue;   // quad-uniform: shuffles stay safe

        const float* ps = seq  + (size_t)row * 256 + q4;
        const float* pt = seq1 + (size_t)row * 256 + q4;

        float acc[8];
#pragma unroll
        for (int k = 0; k < 8; ++k) acc[k] = 0.0f;

#pragma unroll 4
        for (int i = 0; i < 16; ++i) {
            const int col = (i << 4) + q4;
            // seq: non-temporal (nt) -> no L2/L3 allocation; keeps seq1
            // resident in the 256MB Infinity Cache.
            const f32x4 s = __builtin_nontemporal_load(
                                (const f32x4*)(ps + (i << 4)));
            const f32x4 t = *(const f32x4*)(pt + (i << 4));
            const float4 cf = *(const float4*)&s_coef[col];

            const float r0 = elu1(cf.x * s[0]) + 0.1f * t[0];
            const float r1 = elu1(cf.y * s[1]) + 0.1f * t[1];
            const float r2 = elu1(cf.z * s[2]) + 0.1f * t[2];
            const float r3 = elu1(cf.w * s[3]) + 0.1f * t[3];

            acc[7] += r0 * r0 + r1 * r1 + r2 * r2 + r3 * r3;
#pragma unroll
            for (int c = 0; c < 7; ++c) {
                const float4 av = *(const float4*)&s_ave[c][col];
                acc[c] += r0 * av.x + r1 * av.y + r2 * av.z + r3 * av.w;
            }
        }

        // reduce the 8 partials across the 4 lanes of this row's group
#pragma unroll
        for (int off = 1; off <= 2; off <<= 1) {
#pragma unroll
            for (int k = 0; k < 8; ++k)
                acc[k] += __shfl_xor(acc[k], off, 64);
        }

        // softmax over cosine sims (redundant x4 within the group)
        const float nr = sqrtf(acc[7]);
        float sims[7];
        float m = -INFINITY;
#pragma unroll
        for (int c = 0; c < 7; ++c) {
            const float den = fmaxf(nr * na[c], 1e-8f);
            sims[c] = acc[c] * __builtin_amdgcn_rcpf(den);
            m = fmaxf(m, sims[c]);
        }
        float e[7], sum = 0.0f;
#pragma unroll
        for (int c = 0; c < 7; ++c) {
            e[c] = __expf(sims[c] - m);
            sum += e[c];
        }
        const float inv = __builtin_amdgcn_rcpf(sum);

        // lane q writes c=q, and c=q+4 for q<3 (static indices only)
        const float eq  = (q == 0) ? e[0] : (q == 1) ? e[1]
                        : (q == 2) ? e[2] : e[3];
        const float eq4 = (q == 0) ? e[4] : (q == 1) ? e[5] : e[6];

        float* po = out + (size_t)row * 7;
        po[q] = eq * inv;
        if (q < 3) po[q + 4] = eq4 * inv;
    }
}

extern "C" void kernel_launch(void* const* d_in, const int* in_sizes, int n_in,
                              void* d_out, int out_size, void* d_ws, size_t ws_size,
                              hipStream_t stream) {
    const float* seq    = (const float*)d_in[0];
    const float* seq1   = (const float*)d_in[1];
    const float* prompt = (const float*)d_in[2];
    const float* w_np   = (const float*)d_in[3];
    const float* w_ds   = (const float*)d_in[4];
    const float* w_df   = (const float*)d_in[5];
    const float* ave    = (const float*)d_in[6];
    float* out = (float*)d_out;

    const int N = in_sizes[0] / 256;          // 200000
    const int ngroups = (N + 15) / 16;        // 12500 row-groups of 16
    const int wavesPerBlock = 4;
    // one 16-row group per wave: 3125 blocks = 12500 waves
    int blocks = (ngroups + wavesPerBlock - 1) / wavesPerBlock;
    if (blocks < 1) blocks = 1;

    downprompt_kernel<<<blocks, 256, 0, stream>>>(seq, seq1, prompt, w_np, w_ds,
                                                  w_df, ave, out, N);
}

// Round 8
// 403.502 us; speedup vs baseline: 1.0467x; 1.0467x over previous
//
#include <hip/hip_runtime.h>
#include <math.h>

// downprompt: fused elementwise + 7-way cosine-sim + softmax.
// v9: decisive probe — pure-HBM streaming (nt on BOTH inputs + nt stores).
// Evidence so far: v0/v3/v7/v8 (four schedules, incl. a clean L3/HBM
// partition in v8) all converge at ~2.95 TB/s delivered read. v8 proved
// the partition took effect (FETCH split as predicted) yet time was flat:
// L3-hit path and HBM path did NOT add. Hypotheses: (A) shared service
// stage (XCD fabric ingress / platform read ceiling ~3.1 TB/s = m13 copy
// read-half) -> nt-on-both is flat -> ROOFLINE; (B) L3-hit service is the
// slow stage -> pure-HBM stream is faster. FETCH_SIZE must read ~410MB
// for the probe to be valid.
// Structure: v8's (best, 138.8us): 4 lanes/row x 16 rows/wave, coef+ave
// in LDS broadcast, 2-round quad reduction, x4-redundant epilogue.

typedef float f32x4 __attribute__((ext_vector_type(4)));

__device__ __forceinline__ float elu1(float x) {
    return x > 0.0f ? x : __expf(x) - 1.0f;
}

__device__ __forceinline__ float wave_sum(float v) {
#pragma unroll
    for (int off = 32; off > 0; off >>= 1)
        v += __shfl_xor(v, off, 64);
    return v;
}

__global__ __launch_bounds__(256) void downprompt_kernel(
    const float* __restrict__ seq,
    const float* __restrict__ seq1,
    const float* __restrict__ prompt,
    const float* __restrict__ w_np,
    const float* __restrict__ w_ds,
    const float* __restrict__ w_df,
    const float* __restrict__ ave,
    float* __restrict__ out,
    int N)
{
    __shared__ float s_coef[256];
    __shared__ float s_ave[7][256];

    const int tid  = threadIdx.x;
    const int lane = tid & 63;

    // ---- block setup: stage coef[d] and ave into LDS ----
    {
        const float a  = w_df[0];
        const float b  = w_df[1];
        const float w0 = w_np[0], w1 = w_np[1], w2 = w_np[2];
        const float pr = w0 * prompt[tid] + w1 * prompt[256 + tid]
                       + w2 * prompt[512 + tid];
        s_coef[tid] = a * (1.0f + elu1(pr)) + b * w_ds[tid];
#pragma unroll
        for (int c = 0; c < 7; ++c)
            s_ave[c][tid] = ave[c * 256 + tid];
    }
    __syncthreads();

    // ---- per-wave: prototype norms (once per wave) ----
    float na[7];
#pragma unroll
    for (int c = 0; c < 7; ++c) {
        const float4 v = *(const float4*)&s_ave[c][lane << 2];
        na[c] = sqrtf(wave_sum(v.x * v.x + v.y * v.y + v.z * v.z + v.w * v.w));
    }

    // ---- 4 lanes per row, 16 rows per wave ----
    const int q   = lane & 3;    // column phase (0..3)
    const int q4  = q << 2;
    const int sub = lane >> 2;   // row within group (0..15)
    const int wavesPerBlock = blockDim.x >> 6;
    const int gwave = blockIdx.x * wavesPerBlock + (tid >> 6);
    const int nwave = gridDim.x * wavesPerBlock;
    const int ngroups = (N + 15) >> 4;

    for (int g = gwave; g < ngroups; g += nwave) {
        const int row = (g << 4) + sub;
        if (row >= N) continue;   // quad-uniform: shuffles stay safe

        const float* ps = seq  + (size_t)row * 256 + q4;
        const float* pt = seq1 + (size_t)row * 256 + q4;

        float acc[8];
#pragma unroll
        for (int k = 0; k < 8; ++k) acc[k] = 0.0f;

#pragma unroll 4
        for (int i = 0; i < 16; ++i) {
            const int col = (i << 4) + q4;
            // both streams non-temporal: no L2/L3 allocation, pure HBM
            const f32x4 s = __builtin_nontemporal_load(
                                (const f32x4*)(ps + (i << 4)));
            const f32x4 t = __builtin_nontemporal_load(
                                (const f32x4*)(pt + (i << 4)));
            const float4 cf = *(const float4*)&s_coef[col];

            const float r0 = elu1(cf.x * s[0]) + 0.1f * t[0];
            const float r1 = elu1(cf.y * s[1]) + 0.1f * t[1];
            const float r2 = elu1(cf.z * s[2]) + 0.1f * t[2];
            const float r3 = elu1(cf.w * s[3]) + 0.1f * t[3];

            acc[7] += r0 * r0 + r1 * r1 + r2 * r2 + r3 * r3;
#pragma unroll
            for (int c = 0; c < 7; ++c) {
                const float4 av = *(const float4*)&s_ave[c][col];
                acc[c] += r0 * av.x + r1 * av.y + r2 * av.z + r3 * av.w;
            }
        }

        // reduce the 8 partials across the 4 lanes of this row's group
#pragma unroll
        for (int off = 1; off <= 2; off <<= 1) {
#pragma unroll
            for (int k = 0; k < 8; ++k)
                acc[k] += __shfl_xor(acc[k], off, 64);
        }

        // softmax over cosine sims (redundant x4 within the group)
        const float nr = sqrtf(acc[7]);
        float sims[7];
        float m = -INFINITY;
#pragma unroll
        for (int c = 0; c < 7; ++c) {
            const float den = fmaxf(nr * na[c], 1e-8f);
            sims[c] = acc[c] * __builtin_amdgcn_rcpf(den);
            m = fmaxf(m, sims[c]);
        }
        float e[7], sum = 0.0f;
#pragma unroll
        for (int c = 0; c < 7; ++c) {
            e[c] = __expf(sims[c] - m);
            sum += e[c];
        }
        const float inv = __builtin_amdgcn_rcpf(sum);

        // lane q writes c=q, and c=q+4 for q<3 (static indices only)
        const float eq  = (q == 0) ? e[0] : (q == 1) ? e[1]
                        : (q == 2) ? e[2] : e[3];
        const float eq4 = (q == 0) ? e[4] : (q == 1) ? e[5] : e[6];

        float* po = out + (size_t)row * 7;
        __builtin_nontemporal_store(eq * inv, po + q);
        if (q < 3) __builtin_nontemporal_store(eq4 * inv, po + q + 4);
    }
}

extern "C" void kernel_launch(void* const* d_in, const int* in_sizes, int n_in,
                              void* d_out, int out_size, void* d_ws, size_t ws_size,
                              hipStream_t stream) {
    const float* seq    = (const float*)d_in[0];
    const float* seq1   = (const float*)d_in[1];
    const float* prompt = (const float*)d_in[2];
    const float* w_np   = (const float*)d_in[3];
    const float* w_ds   = (const float*)d_in[4];
    const float* w_df   = (const float*)d_in[5];
    const float* ave    = (const float*)d_in[6];
    float* out = (float*)d_out;

    const int N = in_sizes[0] / 256;          // 200000
    const int ngroups = (N + 15) / 16;        // 12500 row-groups of 16
    const int wavesPerBlock = 4;
    // one 16-row group per wave: 3125 blocks = 12500 waves
    int blocks = (ngroups + wavesPerBlock - 1) / wavesPerBlock;
    if (blocks < 1) blocks = 1;

    downprompt_kernel<<<blocks, 256, 0, stream>>>(seq, seq1, prompt, w_np, w_ds,
                                                  w_df, ave, out, N);
}

// Round 9
// 384.641 us; speedup vs baseline: 1.0980x; 1.0490x over previous
//
#include <hip/hip_runtime.h>
#include <math.h>

// downprompt: fused elementwise + 7-way cosine-sim + softmax.
// v10: full-cache-line read requests. Evidence: nt-on-both (v9) beat the
// L3 path (~120us, 3.4 TB/s read), and the harness fill kernel proves the
// write path does 6.7 TB/s with line-contiguous requests while our
// 64B-scattered reads cap at ~3.3 -> hypothesis: read path is REQUEST-
// RATE limited, so request full 128B lines. Geometry: 8 lanes per row x
// 8 rows per wave — each instruction reads 8 aligned 128B lines (8 lanes
// x 16B contiguous per row). nt loads/stores throughout (no L3 alloc).
// coef+ave in LDS (8-way broadcast, conflict-free), 3-round butterfly,
// x8-redundant epilogue, lane ph<7 writes exactly one output element.

typedef float f32x4 __attribute__((ext_vector_type(4)));

__device__ __forceinline__ float elu1(float x) {
    return x > 0.0f ? x : __expf(x) - 1.0f;
}

__device__ __forceinline__ float wave_sum(float v) {
#pragma unroll
    for (int off = 32; off > 0; off >>= 1)
        v += __shfl_xor(v, off, 64);
    return v;
}

__global__ __launch_bounds__(256) void downprompt_kernel(
    const float* __restrict__ seq,
    const float* __restrict__ seq1,
    const float* __restrict__ prompt,
    const float* __restrict__ w_np,
    const float* __restrict__ w_ds,
    const float* __restrict__ w_df,
    const float* __restrict__ ave,
    float* __restrict__ out,
    int N)
{
    __shared__ float s_coef[256];
    __shared__ float s_ave[7][256];

    const int tid  = threadIdx.x;
    const int lane = tid & 63;

    // ---- block setup: stage coef[d] and ave into LDS ----
    {
        const float a  = w_df[0];
        const float b  = w_df[1];
        const float w0 = w_np[0], w1 = w_np[1], w2 = w_np[2];
        const float pr = w0 * prompt[tid] + w1 * prompt[256 + tid]
                       + w2 * prompt[512 + tid];
        s_coef[tid] = a * (1.0f + elu1(pr)) + b * w_ds[tid];
#pragma unroll
        for (int c = 0; c < 7; ++c)
            s_ave[c][tid] = ave[c * 256 + tid];
    }
    __syncthreads();

    // ---- per-wave: prototype norms (once per wave) ----
    float na[7];
#pragma unroll
    for (int c = 0; c < 7; ++c) {
        const float4 v = *(const float4*)&s_ave[c][lane << 2];
        na[c] = sqrtf(wave_sum(v.x * v.x + v.y * v.y + v.z * v.z + v.w * v.w));
    }

    // ---- 8 lanes per row, 8 rows per wave ----
    const int ph  = lane & 7;    // 16B phase within a 128B line (0..7)
    const int ph4 = ph << 2;     // float offset of this lane's 16B
    const int sub = lane >> 3;   // row within group (0..7)
    const int wavesPerBlock = blockDim.x >> 6;
    const int gwave = blockIdx.x * wavesPerBlock + (tid >> 6);
    const int nwave = gridDim.x * wavesPerBlock;
    const int ngroups = (N + 7) >> 3;

    for (int g = gwave; g < ngroups; g += nwave) {
        const int row = (g << 3) + sub;
        if (row >= N) continue;   // group-uniform: shuffles stay safe

        const float* ps = seq  + (size_t)row * 256 + ph4;
        const float* pt = seq1 + (size_t)row * 256 + ph4;

        float acc[8];
#pragma unroll
        for (int k = 0; k < 8; ++k) acc[k] = 0.0f;

        // iter i: this row's 8 lanes read floats [i*32 .. i*32+31] —
        // one aligned 128B line per row per instruction.
#pragma unroll
        for (int i = 0; i < 8; ++i) {
            const int col = (i << 5) + ph4;
            const f32x4 s = __builtin_nontemporal_load(
                                (const f32x4*)(ps + (i << 5)));
            const f32x4 t = __builtin_nontemporal_load(
                                (const f32x4*)(pt + (i << 5)));
            const float4 cf = *(const float4*)&s_coef[col];

            const float r0 = elu1(cf.x * s[0]) + 0.1f * t[0];
            const float r1 = elu1(cf.y * s[1]) + 0.1f * t[1];
            const float r2 = elu1(cf.z * s[2]) + 0.1f * t[2];
            const float r3 = elu1(cf.w * s[3]) + 0.1f * t[3];

            acc[7] += r0 * r0 + r1 * r1 + r2 * r2 + r3 * r3;
#pragma unroll
            for (int c = 0; c < 7; ++c) {
                const float4 av = *(const float4*)&s_ave[c][col];
                acc[c] += r0 * av.x + r1 * av.y + r2 * av.z + r3 * av.w;
            }
        }

        // reduce the 8 partials across the 8 lanes of this row's group
#pragma unroll
        for (int off = 1; off <= 4; off <<= 1) {
#pragma unroll
            for (int k = 0; k < 8; ++k)
                acc[k] += __shfl_xor(acc[k], off, 64);
        }

        // softmax over cosine sims (redundant x8 within the group)
        const float nr = sqrtf(acc[7]);
        float sims[7];
        float m = -INFINITY;
#pragma unroll
        for (int c = 0; c < 7; ++c) {
            const float den = fmaxf(nr * na[c], 1e-8f);
            sims[c] = acc[c] * __builtin_amdgcn_rcpf(den);
            m = fmaxf(m, sims[c]);
        }
        float e[7], sum = 0.0f;
#pragma unroll
        for (int c = 0; c < 7; ++c) {
            e[c] = __expf(sims[c] - m);
            sum += e[c];
        }
        const float inv = __builtin_amdgcn_rcpf(sum);

        // lane ph (<7) writes exactly class c=ph (static per-lane select)
        float mye = e[0];
#pragma unroll
        for (int c = 1; c < 7; ++c)
            if (ph == c) mye = e[c];

        if (ph < 7)
            __builtin_nontemporal_store(mye * inv, out + (size_t)row * 7 + ph);
    }
}

extern "C" void kernel_launch(void* const* d_in, const int* in_sizes, int n_in,
                              void* d_out, int out_size, void* d_ws, size_t ws_size,
                              hipStream_t stream) {
    const float* seq    = (const float*)d_in[0];
    const float* seq1   = (const float*)d_in[1];
    const float* prompt = (const float*)d_in[2];
    const float* w_np   = (const float*)d_in[3];
    const float* w_ds   = (const float*)d_in[4];
    const float* w_df   = (const float*)d_in[5];
    const float* ave    = (const float*)d_in[6];
    float* out = (float*)d_out;

    const int N = in_sizes[0] / 256;          // 200000
    const int ngroups = (N + 7) / 8;          // 25000 row-groups of 8
    const int wavesPerBlock = 4;
    // one 8-row group per wave: 6250 blocks = 25000 waves
    int blocks = (ngroups + wavesPerBlock - 1) / wavesPerBlock;
    if (blocks < 1) blocks = 1;

    downprompt_kernel<<<blocks, 256, 0, stream>>>(seq, seq1, prompt, w_np, w_ds,
                                                  w_df, ave, out, N);
}